// Round 12
// baseline (273.188 us; speedup 1.0000x reference)
//
#include <hip/hip_runtime.h>
#include <hip/hip_bf16.h>

// Problem dims
#define B_  32
#define C_  16
#define Hh  64
#define Ww  64
#define O_  256
#define Kk  5
#define Ho_ 60
#define Wo_ 60
#define Dd  400                 // C*K*K
#define Nn  (B_*Ho_*Wo_)        // 115200
#define NY  ((size_t)B_*O_*Ho_*Wo_)  // 29491200
#define ACAP 16384
#define TAU 2.5e-4f             // top-2 gap threshold (bf16x3 max err ~1e-5)

typedef float f4 __attribute__((ext_vector_type(4)));
typedef float f32x16 __attribute__((ext_vector_type(16)));
typedef unsigned int u32x2 __attribute__((ext_vector_type(2)));
typedef unsigned int u32x4 __attribute__((ext_vector_type(4)));
typedef __bf16 bf16x8 __attribute__((ext_vector_type(8)));

static __device__ __forceinline__ void bf16split(float v, unsigned short& h, unsigned short& l) {
    __hip_bfloat16 bh = __float2bfloat16(v);
    float vh = __bfloat162float(bh);
    __hip_bfloat16 bl = __float2bfloat16(v - vh);
    h = __builtin_bit_cast(unsigned short, bh);
    l = __builtin_bit_cast(unsigned short, bl);
}

// ---- prep: pack w as MFMA-A fragments (32x32x16), bf16 hi/lo planes ----
// Step u = jc*5 + s5 (25 steps). A lane (q2=L>>5, r32=L&31), elem j:
// m = o-within-tile = r32, k = 8q2+j -> g = 16*s5 + 8*q2 + j (g<80 always).
// wpk[u][ot][L][j] (u16), value = w[32*ot + r32][g*5 + jc].
__global__ void prep_kernel(const float* __restrict__ w, unsigned short* __restrict__ wpkH,
                            unsigned short* __restrict__ wpkL, int* __restrict__ count,
                            int* __restrict__ acnt) {
    const int u = blockIdx.x;           // 0..24
    const int jc = u / 5, s5 = u - (u / 5) * 5;
    const int tid = threadIdx.x;
    const int ot = tid >> 5, r32 = tid & 31;   // ot 0..7
    const int o = 32 * ot + r32;
    #pragma unroll
    for (int q2 = 0; q2 < 2; ++q2) {
        unsigned short h[8], l[8];
        #pragma unroll
        for (int j = 0; j < 8; ++j) {
            int g = 16 * s5 + 8 * q2 + j;
            bf16split(w[o * Dd + g * 5 + jc], h[j], l[j]);
        }
        const size_t off = ((size_t)(u * 8 + ot) * 64 + (r32 + 32 * q2)) * 8;
        u32x4 ph = { (unsigned)h[0] | ((unsigned)h[1] << 16), (unsigned)h[2] | ((unsigned)h[3] << 16),
                     (unsigned)h[4] | ((unsigned)h[5] << 16), (unsigned)h[6] | ((unsigned)h[7] << 16) };
        u32x4 pl = { (unsigned)l[0] | ((unsigned)l[1] << 16), (unsigned)l[2] | ((unsigned)l[3] << 16),
                     (unsigned)l[4] | ((unsigned)l[5] << 16), (unsigned)l[6] | ((unsigned)l[7] << 16) };
        *reinterpret_cast<u32x4*>(wpkH + off) = ph;
        *reinterpret_cast<u32x4*>(wpkL + off) = pl;
    }
    if (u == 0) { count[tid] = 0; if (tid == 0) *acnt = 0; }
}

// ---- phase 1: 32x32x16 bf16x3 MFMA conv (A=w, B=x) + top2 argmax + appends ----
// grid 1920 (b,ho); 4 waves; wave wv: o in [64wv,64wv+64) (ot pair 2wv,2wv+1).
// D[m=o][n=wo]: wo = lane&31 (+32wt), o = 64wv+32ot+(reg&3)+8(reg>>2)+4*(lane>>5).
// launch_bounds(256,4): 4 blocks/CU (LDS 30.7K*4=123K<=160K; regs 48 arch + 64 acc = 112 <= 128).
__launch_bounds__(256, 4)
__global__ void conv_mfma_kernel(const float* __restrict__ x, const unsigned short* __restrict__ wpkH,
                                 const unsigned short* __restrict__ wpkL, float* __restrict__ y,
                                 int* __restrict__ count, int* __restrict__ lw_n,
                                 float* __restrict__ lw_s, int* __restrict__ acnt,
                                 int* __restrict__ ambig, int cap) {
    __shared__ __align__(16) unsigned short xT[2 * 7072];   // [plane][v 0..67][g 0..103(pad)]
    __shared__ float wm1[4][64], wm2[4][64];
    __shared__ float rowM1[64];

    const int tid = threadIdx.x;
    const int L = tid & 63, wv = tid >> 6;
    const int q2 = L >> 5, r32 = L & 31;
    const int b = blockIdx.x / Ho_, ho = blockIdx.x % Ho_;

    // zero rows v=64..67 (cols 0..79), both planes
    if (tid < 80) {
        u32x4 z = { 0, 0, 0, 0 };
        int plane = tid / 40, rem = tid % 40, row = 64 + rem / 10, blk = rem % 10;
        *reinterpret_cast<u32x4*>(&xT[plane * 7072 + row * 104 + blk * 8]) = z;
    }

    // stage x transposed (column-gather): thread (v=tid&63, seg=tid>>6), g in [20seg,20seg+20)
    {
        const float* xb = x + (size_t)b * (C_ * Hh * Ww);
        const int v = tid & 63;
        const int seg = tid >> 6;
        const int segc = seg * 4;
        #pragma unroll
        for (int qg = 0; qg < 5; ++qg) {
            unsigned short h[4], l[4];
            #pragma unroll
            for (int gg = 0; gg < 4; ++gg) {
                const int k = qg * 4 + gg;
                const int kc = k / 5, ki = k % 5;
                float val = xb[((segc + kc) * Hh + ho + ki) * Ww + v];
                bf16split(val, h[gg], l[gg]);
            }
            const int g0 = seg * 20 + qg * 4;
            u32x2 ph = { (unsigned)h[0] | ((unsigned)h[1] << 16),
                         (unsigned)h[2] | ((unsigned)h[3] << 16) };
            u32x2 pl = { (unsigned)l[0] | ((unsigned)l[1] << 16),
                         (unsigned)l[2] | ((unsigned)l[3] << 16) };
            *reinterpret_cast<u32x2*>(&xT[v * 104 + g0]) = ph;
            *reinterpret_cast<u32x2*>(&xT[7072 + v * 104 + g0]) = pl;
        }
    }

    f32x16 acc[2][2];   // [ot][wt]
    #pragma unroll
    for (int ot = 0; ot < 2; ++ot)
        #pragma unroll
        for (int wt = 0; wt < 2; ++wt)
            #pragma unroll
            for (int i = 0; i < 16; ++i) acc[ot][wt][i] = 0.f;

    __syncthreads();

    // A (weights) per-lane stream base: step u, tile ot -> 16B at u*4096 + (2wv+ot)*512 + L*8
    const unsigned short* ah0 = wpkH + (size_t)(2 * wv) * 512 + (size_t)L * 8;
    const unsigned short* al0 = wpkL + (size_t)(2 * wv) * 512 + (size_t)L * 8;

    u32x4 A0H[2], A0L[2], A1H[2], A1L[2];
    #pragma unroll
    for (int ot = 0; ot < 2; ++ot) {
        A0H[ot] = *reinterpret_cast<const u32x4*>(ah0 + ot * 512);
        A0L[ot] = *reinterpret_cast<const u32x4*>(al0 + ot * 512);
    }

    #pragma unroll
    for (int u = 0; u < 25; ++u) {
        u32x4* AH = (u & 1) ? A1H : A0H;
        u32x4* AL = (u & 1) ? A1L : A0L;
        u32x4* NH = (u & 1) ? A0H : A1H;
        u32x4* NL = (u & 1) ? A0L : A1L;
        if (u < 24) {
            #pragma unroll
            for (int ot = 0; ot < 2; ++ot) {
                NH[ot] = *reinterpret_cast<const u32x4*>(ah0 + (u + 1) * 4096 + ot * 512);
                NL[ot] = *reinterpret_cast<const u32x4*>(al0 + (u + 1) * 4096 + ot * 512);
            }
        }
        const int jc = u / 5, s5 = u % 5;              // compile-time
        u32x4 BH[2], BL[2];
        #pragma unroll
        for (int wt = 0; wt < 2; ++wt) {
            const int bbase = (32 * wt + r32 + jc) * 104 + 16 * s5 + 8 * q2;
            BH[wt] = *reinterpret_cast<const u32x4*>(&xT[bbase]);
            BL[wt] = *reinterpret_cast<const u32x4*>(&xT[7072 + bbase]);
        }
        #pragma unroll
        for (int ot = 0; ot < 2; ++ot) {
            bf16x8 Ah = __builtin_bit_cast(bf16x8, AH[ot]);
            bf16x8 Al = __builtin_bit_cast(bf16x8, AL[ot]);
            #pragma unroll
            for (int wt = 0; wt < 2; ++wt) {
                bf16x8 Bh = __builtin_bit_cast(bf16x8, BH[wt]);
                bf16x8 Bl = __builtin_bit_cast(bf16x8, BL[wt]);
                acc[ot][wt] = __builtin_amdgcn_mfma_f32_32x32x16_bf16(Ah, Bh, acc[ot][wt], 0, 0, 0);
                acc[ot][wt] = __builtin_amdgcn_mfma_f32_32x32x16_bf16(Ah, Bl, acc[ot][wt], 0, 0, 0);
                acc[ot][wt] = __builtin_amdgcn_mfma_f32_32x32x16_bf16(Al, Bh, acc[ot][wt], 0, 0, 0);
            }
        }
    }

    // ---- per-wo top-2 over this wave's 64 o's: in-lane 32 vals, then lane^32, then LDS
    #pragma unroll
    for (int wt = 0; wt < 2; ++wt) {
        float m1 = -__builtin_inff(), m2 = -__builtin_inff();
        #pragma unroll
        for (int ot = 0; ot < 2; ++ot)
            #pragma unroll
            for (int i = 0; i < 16; ++i) {
                float v = acc[ot][wt][i];
                m2 = fmaxf(m2, fminf(m1, v));
                m1 = fmaxf(m1, v);
            }
        float o1 = __shfl_xor(m1, 32), o2 = __shfl_xor(m2, 32);
        m2 = fmaxf(fminf(m1, o1), fmaxf(m2, o2));
        m1 = fmaxf(m1, o1);
        if (q2 == 0) { wm1[wv][32 * wt + r32] = m1; wm2[wv][32 * wt + r32] = m2; }
    }
    __syncthreads();
    if (tid < 64) {
        const int p = tid;
        float M1 = wm1[0][p], M2 = wm2[0][p];
        #pragma unroll
        for (int w2 = 1; w2 < 4; ++w2) {
            float c1 = wm1[w2][p], c2 = wm2[w2][p];
            M2 = fmaxf(fminf(M1, c1), fmaxf(M2, c2));
            M1 = fmaxf(M1, c1);
        }
        bool amb = (M1 - M2) < TAU;
        if (amb && p < Wo_) {
            int n = (b * Ho_ + ho) * Wo_ + p;
            int pos = atomicAdd(acnt, 1);
            if (pos < ACAP) ambig[pos] = n;
        }
        rowM1[p] = amb ? __builtin_inff() : M1;
    }
    __syncthreads();

    // ---- winner appends (exact equality vs block max; ties append all)
    #pragma unroll
    for (int wt = 0; wt < 2; ++wt) {
        const int wo = 32 * wt + r32;
        if (wo < Wo_) {
            const float M = rowM1[wo];
            const int n = (b * Ho_ + ho) * Wo_ + wo;
            #pragma unroll
            for (int ot = 0; ot < 2; ++ot)
                #pragma unroll
                for (int i = 0; i < 16; ++i) {
                    if (acc[ot][wt][i] == M) {
                        int o = 64 * wv + 32 * ot + (i & 3) + 8 * (i >> 2) + 4 * q2;
                        int pos = atomicAdd(&count[o], 1);
                        if (pos < cap) { lw_n[o * cap + pos] = n; lw_s[o * cap + pos] = M; }
                    }
                }
        }
    }

    // ---- y stores: per reg, lanes span 32 consecutive wo (coalesced 128B per half-wave)
    #pragma unroll
    for (int ot = 0; ot < 2; ++ot)
        #pragma unroll
        for (int wt = 0; wt < 2; ++wt) {
            const int wo = 32 * wt + r32;
            if (wo < Wo_) {
                #pragma unroll
                for (int i = 0; i < 16; ++i) {
                    const int o = 64 * wv + 32 * ot + (i & 3) + 8 * (i >> 2) + 4 * q2;
                    y[((size_t)(b * O_ + o) * Ho_ + ho) * (size_t)Wo_ + wo] = acc[ot][wt][i];
                }
            }
        }
}

// ---- fallback: exact fp32 re-resolve of ambiguous rows ----
__global__ void fallback_kernel(const float* __restrict__ x, const float* __restrict__ w,
                                const int* __restrict__ acnt, const int* __restrict__ ambig,
                                int* __restrict__ count, int* __restrict__ lw_n,
                                float* __restrict__ lw_s, int cap) {
    __shared__ float xrow[Dd];
    __shared__ float red[256];
    int cnt = *acnt; if (cnt > ACAP) cnt = ACAP;
    for (int idx = blockIdx.x; idx < cnt; idx += gridDim.x) {
        const int n = ambig[idx];
        const int bb = n / 3600, rem = n % 3600, hh = rem / 60, ww2 = rem % 60;
        for (int k = threadIdx.x; k < Dd; k += 256) {
            int c = k / 25, rr = k % 25, i = rr / 5, j = rr % 5;
            xrow[k] = x[(((size_t)bb * C_ + c) * Hh + hh + i) * Ww + ww2 + j];
        }
        __syncthreads();
        const int o = threadIdx.x;
        const float* wr = w + (size_t)o * Dd;
        float s = 0.f;
        #pragma unroll 4
        for (int k = 0; k < Dd; ++k) s = fmaf(xrow[k], wr[k], s);
        red[o] = s;
        __syncthreads();
        #pragma unroll
        for (int st = 128; st >= 1; st >>= 1) {
            if (o < st) red[o] = fmaxf(red[o], red[o + st]);
            __syncthreads();
        }
        const float mx = red[0];
        if (s == mx) {
            int pos = atomicAdd(&count[o], 1);
            if (pos < cap) { lw_n[o * cap + pos] = n; lw_s[o * cap + pos] = s; }
        }
        __syncthreads();
    }
}

// ---- phase 2a: per-slice partial sums (4 slices per o) ----
__global__ void delta_part_kernel(const float* __restrict__ x,
                                  const int* __restrict__ count, const int* __restrict__ lw_n,
                                  const float* __restrict__ lw_s, float* __restrict__ partial,
                                  float* __restrict__ ssum_part, int cap) {
    const int o   = blockIdx.x >> 2;
    const int sl  = blockIdx.x & 3;
    const int tid = threadIdx.x;
    int cnt = count[o]; if (cnt > cap) cnt = cap;
    const int e0 = (cnt * sl) >> 2;
    const int e1 = (cnt * (sl + 1)) >> 2;

    const int d0 = tid;
    const int c0 = d0 / 25, r0 = d0 % 25, i0 = r0 / 5, j0 = r0 % 5;
    const bool has1 = (tid < Dd - 256);
    const int dd1 = has1 ? tid + 256 : 0;
    const int c1 = dd1 / 25, r1 = dd1 % 25, i1 = r1 / 5, j1 = r1 % 5;

    const int* ln = lw_n + (size_t)o * cap;
    const float* ls = lw_s + (size_t)o * cap;

    float acc0 = 0.f, acc1 = 0.f, ssum = 0.f;
    int   nn = (e0 < e1) ? ln[e0] : 0;
    float sn = (e0 < e1) ? ls[e0] : 0.f;
    for (int e = e0; e < e1; ++e) {
        const int n = nn; const float s = sn;
        if (e + 1 < e1) { nn = ln[e + 1]; sn = ls[e + 1]; }
        const int bb = n / 3600;
        const int rem = n - bb * 3600;
        const int hh = rem / 60;
        const int ww2 = rem - hh * 60;
        ssum += s;
        const float* xb = x + (size_t)bb * (C_ * Hh * Ww);
        acc0 += s * xb[(c0 * Hh + hh + i0) * Ww + ww2 + j0];
        if (has1) acc1 += s * xb[(c1 * Hh + hh + i1) * Ww + ww2 + j1];
    }
    float* pp = partial + ((size_t)o * 4 + sl) * Dd;
    pp[tid] = acc0;
    if (has1) pp[tid + 256] = acc1;
    if (tid == 0) ssum_part[o * 4 + sl] = ssum;
}

// ---- phase 2b: reduce partials, apply -ssum/N * w ----
__global__ void delta_reduce_kernel(const float* __restrict__ w, const float* __restrict__ partial,
                                    const float* __restrict__ ssum_part,
                                    float* __restrict__ dout) {
    const int o = blockIdx.x, tid = threadIdx.x;
    const float ssum = ssum_part[o * 4] + ssum_part[o * 4 + 1]
                     + ssum_part[o * 4 + 2] + ssum_part[o * 4 + 3];
    const float invN = 1.0f / (float)Nn;
    const float* pp = partial + (size_t)o * 4 * Dd;
    float a0 = pp[tid] + pp[Dd + tid] + pp[2 * Dd + tid] + pp[3 * Dd + tid];
    dout[NY + (size_t)o * Dd + tid] = a0 * invN - ssum * invN * w[o * Dd + tid];
    if (tid < Dd - 256) {
        const int t2 = tid + 256;
        float a1 = pp[t2] + pp[Dd + t2] + pp[2 * Dd + t2] + pp[3 * Dd + t2];
        dout[NY + (size_t)o * Dd + t2] = a1 * invN - ssum * invN * w[o * Dd + t2];
    }
}

extern "C" void kernel_launch(void* const* d_in, const int* in_sizes, int n_in,
                              void* d_out, int out_size, void* d_ws, size_t ws_size,
                              hipStream_t stream) {
    (void)in_sizes; (void)n_in; (void)out_size;
    const float* x = (const float*)d_in[0];
    const float* w = (const float*)d_in[1];
    float* out = (float*)d_out;

    char* ws = (char*)d_ws;
    int*            count     = (int*)ws;                          // @0         (1,024 B)
    int*            acnt      = (int*)(ws + 1024);                 // @1,024     (64 B)
    int*            ambig     = (int*)(ws + 1088);                 // @1,088     (65,536 B)
    unsigned short* wpkH      = (unsigned short*)(ws + 66624);     // @66,624    (204,800 B)
    unsigned short* wpkL      = (unsigned short*)(ws + 271424);    // @271,424   (204,800 B)
    float*          partial   = (float*)(ws + 476224);             // @476,224   (1,638,400 B)
    float*          ssum_part = (float*)(ws + 2114624);            // @2,114,624 (4,096 B)
    const size_t base = 2118720;

    size_t avail = (ws_size > base) ? (ws_size - base) : 0;
    long long cap_ll = (long long)(avail / ((size_t)O_ * 8));
    int cap = (int)(cap_ll > 4096 ? 4096 : (cap_ll < 1 ? 1 : cap_ll));

    int*   lw_n = (int*)(ws + base);
    float* lw_s = (float*)(ws + base + (size_t)O_ * cap * 4);

    prep_kernel<<<dim3(25), dim3(256), 0, stream>>>(w, wpkH, wpkL, count, acnt);
    conv_mfma_kernel<<<dim3(B_ * Ho_), dim3(256), 0, stream>>>(x, wpkH, wpkL, out, count, lw_n, lw_s,
                                                               acnt, ambig, cap);
    fallback_kernel<<<dim3(256), dim3(256), 0, stream>>>(x, w, acnt, ambig, count, lw_n, lw_s, cap);
    delta_part_kernel<<<dim3(O_ * 4), dim3(256), 0, stream>>>(x, count, lw_n, lw_s, partial, ssum_part, cap);
    delta_reduce_kernel<<<dim3(O_), dim3(256), 0, stream>>>(w, partial, ssum_part, out);
}

// Round 13
// 240.612 us; speedup vs baseline: 1.1354x; 1.1354x over previous
//
#include <hip/hip_runtime.h>
#include <hip/hip_bf16.h>

// Problem dims
#define B_  32
#define C_  16
#define Hh  64
#define Ww  64
#define O_  256
#define Kk  5
#define Ho_ 60
#define Wo_ 60
#define Dd  400                 // C*K*K
#define Nn  (B_*Ho_*Wo_)        // 115200
#define NY  ((size_t)B_*O_*Ho_*Wo_)  // 29491200
#define ACAP 16384
#define TAU 2.5e-4f             // top-2 gap threshold (bf16x3 max err ~1e-5)
#define NSL 8                   // delta slices per o

typedef float f4 __attribute__((ext_vector_type(4)));
typedef float f32x16 __attribute__((ext_vector_type(16)));
typedef unsigned int u32x2 __attribute__((ext_vector_type(2)));
typedef unsigned int u32x4 __attribute__((ext_vector_type(4)));
typedef __bf16 bf16x8 __attribute__((ext_vector_type(8)));

static __device__ __forceinline__ void bf16split(float v, unsigned short& h, unsigned short& l) {
    __hip_bfloat16 bh = __float2bfloat16(v);
    float vh = __bfloat162float(bh);
    __hip_bfloat16 bl = __float2bfloat16(v - vh);
    h = __builtin_bit_cast(unsigned short, bh);
    l = __builtin_bit_cast(unsigned short, bl);
}

// ---- prep: pack w as MFMA-A fragments (32x32x16), bf16 hi/lo planes ----
__global__ void prep_kernel(const float* __restrict__ w, unsigned short* __restrict__ wpkH,
                            unsigned short* __restrict__ wpkL, int* __restrict__ count,
                            int* __restrict__ acnt) {
    const int u = blockIdx.x;           // 0..24
    const int jc = u / 5, s5 = u - (u / 5) * 5;
    const int tid = threadIdx.x;
    const int ot = tid >> 5, r32 = tid & 31;   // ot 0..7
    const int o = 32 * ot + r32;
    #pragma unroll
    for (int q2 = 0; q2 < 2; ++q2) {
        unsigned short h[8], l[8];
        #pragma unroll
        for (int j = 0; j < 8; ++j) {
            int g = 16 * s5 + 8 * q2 + j;
            bf16split(w[o * Dd + g * 5 + jc], h[j], l[j]);
        }
        const size_t off = ((size_t)(u * 8 + ot) * 64 + (r32 + 32 * q2)) * 8;
        u32x4 ph = { (unsigned)h[0] | ((unsigned)h[1] << 16), (unsigned)h[2] | ((unsigned)h[3] << 16),
                     (unsigned)h[4] | ((unsigned)h[5] << 16), (unsigned)h[6] | ((unsigned)h[7] << 16) };
        u32x4 pl = { (unsigned)l[0] | ((unsigned)l[1] << 16), (unsigned)l[2] | ((unsigned)l[3] << 16),
                     (unsigned)l[4] | ((unsigned)l[5] << 16), (unsigned)l[6] | ((unsigned)l[7] << 16) };
        *reinterpret_cast<u32x4*>(wpkH + off) = ph;
        *reinterpret_cast<u32x4*>(wpkL + off) = pl;
    }
    if (u == 0) { count[tid] = 0; if (tid == 0) *acnt = 0; }
}

// ---- phase 1: 32x32x16 bf16x3 MFMA conv, software-pipelined with sched_barrier ----
__launch_bounds__(256, 3)
__global__ void conv_mfma_kernel(const float* __restrict__ x, const unsigned short* __restrict__ wpkH,
                                 const unsigned short* __restrict__ wpkL, float* __restrict__ y,
                                 int* __restrict__ count, int* __restrict__ lw_n,
                                 float* __restrict__ lw_s, int* __restrict__ acnt,
                                 int* __restrict__ ambig, int cap) {
    __shared__ __align__(16) unsigned short xT[2 * 7072];   // [plane][v 0..67][g 0..103(pad)]
    __shared__ float wm1[4][64], wm2[4][64];
    __shared__ float rowM1[64];

    const int tid = threadIdx.x;
    const int L = tid & 63, wv = tid >> 6;
    const int q2 = L >> 5, r32 = L & 31;
    const int b = blockIdx.x / Ho_, ho = blockIdx.x % Ho_;

    // A (weights) per-lane stream base
    const unsigned short* ah0 = wpkH + (size_t)(2 * wv) * 512 + (size_t)L * 8;
    const unsigned short* al0 = wpkL + (size_t)(2 * wv) * 512 + (size_t)L * 8;

    // A double buffer; issue step-0 loads NOW (independent of LDS staging)
    u32x4 AH_[2][2], AL_[2][2];
    #pragma unroll
    for (int ot = 0; ot < 2; ++ot) {
        AH_[0][ot] = *reinterpret_cast<const u32x4*>(ah0 + ot * 512);
        AL_[0][ot] = *reinterpret_cast<const u32x4*>(al0 + ot * 512);
    }

    // zero rows v=64..67 (cols 0..79), both planes
    if (tid < 80) {
        u32x4 z = { 0, 0, 0, 0 };
        int plane = tid / 40, rem = tid % 40, row = 64 + rem / 10, blk = rem % 10;
        *reinterpret_cast<u32x4*>(&xT[plane * 7072 + row * 104 + blk * 8]) = z;
    }

    // stage x transposed (column-gather)
    {
        const float* xb = x + (size_t)b * (C_ * Hh * Ww);
        const int v = tid & 63;
        const int seg = tid >> 6;
        const int segc = seg * 4;
        #pragma unroll
        for (int qg = 0; qg < 5; ++qg) {
            unsigned short h[4], l[4];
            #pragma unroll
            for (int gg = 0; gg < 4; ++gg) {
                const int k = qg * 4 + gg;
                const int kc = k / 5, ki = k % 5;
                float val = xb[((segc + kc) * Hh + ho + ki) * Ww + v];
                bf16split(val, h[gg], l[gg]);
            }
            const int g0 = seg * 20 + qg * 4;
            u32x2 ph = { (unsigned)h[0] | ((unsigned)h[1] << 16),
                         (unsigned)h[2] | ((unsigned)h[3] << 16) };
            u32x2 pl = { (unsigned)l[0] | ((unsigned)l[1] << 16),
                         (unsigned)l[2] | ((unsigned)l[3] << 16) };
            *reinterpret_cast<u32x2*>(&xT[v * 104 + g0]) = ph;
            *reinterpret_cast<u32x2*>(&xT[7072 + v * 104 + g0]) = pl;
        }
    }

    f32x16 acc[2][2];   // [ot][wt]
    #pragma unroll
    for (int ot = 0; ot < 2; ++ot)
        #pragma unroll
        for (int wt = 0; wt < 2; ++wt)
            #pragma unroll
            for (int i = 0; i < 16; ++i) acc[ot][wt][i] = 0.f;

    __syncthreads();

    // B double buffer; step-0 ds_reads
    u32x4 BH_[2][2], BL_[2][2];
    #pragma unroll
    for (int wt = 0; wt < 2; ++wt) {
        const int bbase = (32 * wt + r32 + 0) * 104 + 0 + 8 * q2;   // jc=0, s5=0
        BH_[0][wt] = *reinterpret_cast<const u32x4*>(&xT[bbase]);
        BL_[0][wt] = *reinterpret_cast<const u32x4*>(&xT[7072 + bbase]);
    }

    #pragma unroll
    for (int u = 0; u < 25; ++u) {
        const int cur = u & 1, nxt = cur ^ 1;
        if (u < 24) {
            // prefetch A for step u+1 (global/L2)
            #pragma unroll
            for (int ot = 0; ot < 2; ++ot) {
                AH_[nxt][ot] = *reinterpret_cast<const u32x4*>(ah0 + (u + 1) * 4096 + ot * 512);
                AL_[nxt][ot] = *reinterpret_cast<const u32x4*>(al0 + (u + 1) * 4096 + ot * 512);
            }
            // prefetch B for step u+1 (LDS)
            const int jcn = (u + 1) / 5, s5n = (u + 1) % 5;        // compile-time
            #pragma unroll
            for (int wt = 0; wt < 2; ++wt) {
                const int bbase = (32 * wt + r32 + jcn) * 104 + 16 * s5n + 8 * q2;
                BH_[nxt][wt] = *reinterpret_cast<const u32x4*>(&xT[bbase]);
                BL_[nxt][wt] = *reinterpret_cast<const u32x4*>(&xT[7072 + bbase]);
            }
        }
        __builtin_amdgcn_sched_barrier(0);   // pin prefetches BEFORE this step's MFMAs
        // 12 MFMAs for step u; product-index outer -> 4 independent chains per group
        #pragma unroll
        for (int p = 0; p < 3; ++p) {
            #pragma unroll
            for (int ot = 0; ot < 2; ++ot) {
                #pragma unroll
                for (int wt = 0; wt < 2; ++wt) {
                    bf16x8 Aop = __builtin_bit_cast(bf16x8, (p == 2) ? AL_[cur][ot] : AH_[cur][ot]);
                    bf16x8 Bop = __builtin_bit_cast(bf16x8, (p == 1) ? BL_[cur][wt] : BH_[cur][wt]);
                    acc[ot][wt] = __builtin_amdgcn_mfma_f32_32x32x16_bf16(Aop, Bop, acc[ot][wt], 0, 0, 0);
                }
            }
        }
    }

    // ---- per-wo top-2 over this wave's 64 o's: in-lane 32 vals, then lane^32, then LDS
    #pragma unroll
    for (int wt = 0; wt < 2; ++wt) {
        float m1 = -__builtin_inff(), m2 = -__builtin_inff();
        #pragma unroll
        for (int ot = 0; ot < 2; ++ot)
            #pragma unroll
            for (int i = 0; i < 16; ++i) {
                float v = acc[ot][wt][i];
                m2 = fmaxf(m2, fminf(m1, v));
                m1 = fmaxf(m1, v);
            }
        float o1 = __shfl_xor(m1, 32), o2 = __shfl_xor(m2, 32);
        m2 = fmaxf(fminf(m1, o1), fmaxf(m2, o2));
        m1 = fmaxf(m1, o1);
        if (q2 == 0) { wm1[wv][32 * wt + r32] = m1; wm2[wv][32 * wt + r32] = m2; }
    }
    __syncthreads();
    if (tid < 64) {
        const int p = tid;
        float M1 = wm1[0][p], M2 = wm2[0][p];
        #pragma unroll
        for (int w2 = 1; w2 < 4; ++w2) {
            float c1 = wm1[w2][p], c2 = wm2[w2][p];
            M2 = fmaxf(fminf(M1, c1), fmaxf(M2, c2));
            M1 = fmaxf(M1, c1);
        }
        bool amb = (M1 - M2) < TAU;
        if (amb && p < Wo_) {
            int n = (b * Ho_ + ho) * Wo_ + p;
            int pos = atomicAdd(acnt, 1);
            if (pos < ACAP) ambig[pos] = n;
        }
        rowM1[p] = amb ? __builtin_inff() : M1;
    }
    __syncthreads();

    // ---- winner appends (exact equality vs block max; ties append all)
    #pragma unroll
    for (int wt = 0; wt < 2; ++wt) {
        const int wo = 32 * wt + r32;
        if (wo < Wo_) {
            const float M = rowM1[wo];
            const int n = (b * Ho_ + ho) * Wo_ + wo;
            #pragma unroll
            for (int ot = 0; ot < 2; ++ot)
                #pragma unroll
                for (int i = 0; i < 16; ++i) {
                    if (acc[ot][wt][i] == M) {
                        int o = 64 * wv + 32 * ot + (i & 3) + 8 * (i >> 2) + 4 * q2;
                        int pos = atomicAdd(&count[o], 1);
                        if (pos < cap) { lw_n[o * cap + pos] = n; lw_s[o * cap + pos] = M; }
                    }
                }
        }
    }

    // ---- y stores: per reg, lanes span 32 consecutive wo (coalesced)
    #pragma unroll
    for (int ot = 0; ot < 2; ++ot)
        #pragma unroll
        for (int wt = 0; wt < 2; ++wt) {
            const int wo = 32 * wt + r32;
            if (wo < Wo_) {
                #pragma unroll
                for (int i = 0; i < 16; ++i) {
                    const int o = 64 * wv + 32 * ot + (i & 3) + 8 * (i >> 2) + 4 * q2;
                    y[((size_t)(b * O_ + o) * Ho_ + ho) * (size_t)Wo_ + wo] = acc[ot][wt][i];
                }
            }
        }
}

// ---- fallback: exact fp32 re-resolve of ambiguous rows ----
__global__ void fallback_kernel(const float* __restrict__ x, const float* __restrict__ w,
                                const int* __restrict__ acnt, const int* __restrict__ ambig,
                                int* __restrict__ count, int* __restrict__ lw_n,
                                float* __restrict__ lw_s, int cap) {
    __shared__ float xrow[Dd];
    __shared__ float red[256];
    int cnt = *acnt; if (cnt > ACAP) cnt = ACAP;
    for (int idx = blockIdx.x; idx < cnt; idx += gridDim.x) {
        const int n = ambig[idx];
        const int bb = n / 3600, rem = n % 3600, hh = rem / 60, ww2 = rem % 60;
        for (int k = threadIdx.x; k < Dd; k += 256) {
            int c = k / 25, rr = k % 25, i = rr / 5, j = rr % 5;
            xrow[k] = x[(((size_t)bb * C_ + c) * Hh + hh + i) * Ww + ww2 + j];
        }
        __syncthreads();
        const int o = threadIdx.x;
        const float* wr = w + (size_t)o * Dd;
        float s = 0.f;
        #pragma unroll 4
        for (int k = 0; k < Dd; ++k) s = fmaf(xrow[k], wr[k], s);
        red[o] = s;
        __syncthreads();
        #pragma unroll
        for (int st = 128; st >= 1; st >>= 1) {
            if (o < st) red[o] = fmaxf(red[o], red[o + st]);
            __syncthreads();
        }
        const float mx = red[0];
        if (s == mx) {
            int pos = atomicAdd(&count[o], 1);
            if (pos < cap) { lw_n[o * cap + pos] = n; lw_s[o * cap + pos] = s; }
        }
        __syncthreads();
    }
}

// ---- phase 2a: per-slice partial sums (NSL slices per o) ----
__global__ void delta_part_kernel(const float* __restrict__ x,
                                  const int* __restrict__ count, const int* __restrict__ lw_n,
                                  const float* __restrict__ lw_s, float* __restrict__ partial,
                                  float* __restrict__ ssum_part, int cap) {
    const int o   = blockIdx.x / NSL;
    const int sl  = blockIdx.x % NSL;
    const int tid = threadIdx.x;
    int cnt = count[o]; if (cnt > cap) cnt = cap;
    const int e0 = (cnt * sl) / NSL;
    const int e1 = (cnt * (sl + 1)) / NSL;

    const int d0 = tid;
    const int c0 = d0 / 25, r0 = d0 % 25, i0 = r0 / 5, j0 = r0 % 5;
    const bool has1 = (tid < Dd - 256);
    const int dd1 = has1 ? tid + 256 : 0;
    const int c1 = dd1 / 25, r1 = dd1 % 25, i1 = r1 / 5, j1 = r1 % 5;

    const int* ln = lw_n + (size_t)o * cap;
    const float* ls = lw_s + (size_t)o * cap;

    float acc0 = 0.f, acc1 = 0.f, ssum = 0.f;
    int   nn = (e0 < e1) ? ln[e0] : 0;
    float sn = (e0 < e1) ? ls[e0] : 0.f;
    for (int e = e0; e < e1; ++e) {
        const int n = nn; const float s = sn;
        if (e + 1 < e1) { nn = ln[e + 1]; sn = ls[e + 1]; }
        const int bb = n / 3600;
        const int rem = n - bb * 3600;
        const int hh = rem / 60;
        const int ww2 = rem - hh * 60;
        ssum += s;
        const float* xb = x + (size_t)bb * (C_ * Hh * Ww);
        acc0 += s * xb[(c0 * Hh + hh + i0) * Ww + ww2 + j0];
        if (has1) acc1 += s * xb[(c1 * Hh + hh + i1) * Ww + ww2 + j1];
    }
    float* pp = partial + ((size_t)o * NSL + sl) * Dd;
    pp[tid] = acc0;
    if (has1) pp[tid + 256] = acc1;
    if (tid == 0) ssum_part[o * NSL + sl] = ssum;
}

// ---- phase 2b: reduce partials, apply -ssum/N * w ----
__global__ void delta_reduce_kernel(const float* __restrict__ w, const float* __restrict__ partial,
                                    const float* __restrict__ ssum_part,
                                    float* __restrict__ dout) {
    const int o = blockIdx.x, tid = threadIdx.x;
    float ssum = 0.f;
    #pragma unroll
    for (int sl = 0; sl < NSL; ++sl) ssum += ssum_part[o * NSL + sl];
    const float invN = 1.0f / (float)Nn;
    const float* pp = partial + (size_t)o * NSL * Dd;
    float a0 = 0.f;
    #pragma unroll
    for (int sl = 0; sl < NSL; ++sl) a0 += pp[sl * Dd + tid];
    dout[NY + (size_t)o * Dd + tid] = a0 * invN - ssum * invN * w[o * Dd + tid];
    if (tid < Dd - 256) {
        const int t2 = tid + 256;
        float a1 = 0.f;
        #pragma unroll
        for (int sl = 0; sl < NSL; ++sl) a1 += pp[sl * Dd + t2];
        dout[NY + (size_t)o * Dd + t2] = a1 * invN - ssum * invN * w[o * Dd + t2];
    }
}

extern "C" void kernel_launch(void* const* d_in, const int* in_sizes, int n_in,
                              void* d_out, int out_size, void* d_ws, size_t ws_size,
                              hipStream_t stream) {
    (void)in_sizes; (void)n_in; (void)out_size;
    const float* x = (const float*)d_in[0];
    const float* w = (const float*)d_in[1];
    float* out = (float*)d_out;

    char* ws = (char*)d_ws;
    int*            count     = (int*)ws;                          // @0         (1,024 B)
    int*            acnt      = (int*)(ws + 1024);                 // @1,024     (64 B)
    int*            ambig     = (int*)(ws + 1088);                 // @1,088     (65,536 B)
    unsigned short* wpkH      = (unsigned short*)(ws + 66624);     // @66,624    (204,800 B)
    unsigned short* wpkL      = (unsigned short*)(ws + 271424);    // @271,424   (204,800 B)
    float*          partial   = (float*)(ws + 476224);             // @476,224   (3,276,800 B)
    float*          ssum_part = (float*)(ws + 3753024);            // @3,753,024 (8,192 B)
    const size_t base = 3761216;

    size_t avail = (ws_size > base) ? (ws_size - base) : 0;
    long long cap_ll = (long long)(avail / ((size_t)O_ * 8));
    int cap = (int)(cap_ll > 4096 ? 4096 : (cap_ll < 1 ? 1 : cap_ll));

    int*   lw_n = (int*)(ws + base);
    float* lw_s = (float*)(ws + base + (size_t)O_ * cap * 4);

    prep_kernel<<<dim3(25), dim3(256), 0, stream>>>(w, wpkH, wpkL, count, acnt);
    conv_mfma_kernel<<<dim3(B_ * Ho_), dim3(256), 0, stream>>>(x, wpkH, wpkL, out, count, lw_n, lw_s,
                                                               acnt, ambig, cap);
    fallback_kernel<<<dim3(256), dim3(256), 0, stream>>>(x, w, acnt, ambig, count, lw_n, lw_s, cap);
    delta_part_kernel<<<dim3(O_ * NSL), dim3(256), 0, stream>>>(x, count, lw_n, lw_s, partial, ssum_part, cap);
    delta_reduce_kernel<<<dim3(O_), dim3(256), 0, stream>>>(w, partial, ssum_part, out);
}